// Round 18
// baseline (228.567 us; speedup 1.0000x reference)
//
#include <hip/hip_runtime.h>
#include <hip/hip_fp16.h>

#define DMODEL 192
#define DINNER 384
#define NPOS   4096   // B*H*W = 4*32*32
#define SEQL   1024   // H*W
#define DSTATE 16
#define DTRANK 12

__device__ __forceinline__ float silu_f(float v) { return v * (1.f / (1.f + __expf(-v))); }
__device__ __forceinline__ int swiz(int s) { return ((s & 31) << 5) | (s >> 5); }

__device__ __forceinline__ int scan_pos(int dir, int l) {
    int s = (dir & 1) ? (SEQL - 1 - l) : l;
    return (dir & 2) ? swiz(s) : s;
}

// ---------------------------------------------------------------------------
// K1: xz = x @ W_in. Wave-uniform x reads, no LDS. 1536 blocks x 256 thr.
// ---------------------------------------------------------------------------
__global__ void k1_inproj(const float* __restrict__ x, const float* __restrict__ W_in,
                          float* __restrict__ x_val, float* __restrict__ gz) {
    const int t = threadIdx.x;
    const int bi = blockIdx.x;
    const int colg = bi % 3;
    const int pos0 = (bi / 3) << 3;
    const int col = colg * 256 + t;

    const float* xr = x + pos0 * DMODEL;

    float acc[8] = {0,0,0,0,0,0,0,0};
    for (int c = 0; c < DMODEL; c += 4) {
        float w0 = W_in[(c + 0) * 768 + col];
        float w1 = W_in[(c + 1) * 768 + col];
        float w2 = W_in[(c + 2) * 768 + col];
        float w3 = W_in[(c + 3) * 768 + col];
#pragma unroll
        for (int g = 0; g < 8; ++g) {
            const float4 xv = *(const float4*)&xr[g * DMODEL + c];
            acc[g] += xv.x * w0 + xv.y * w1 + xv.z * w2 + xv.w * w3;
        }
    }
    if (col < DINNER) {
#pragma unroll
        for (int g = 0; g < 8; ++g) x_val[(pos0 + g) * DINNER + col] = acc[g];
    } else {
#pragma unroll
        for (int g = 0; g < 8; ++g) gz[(pos0 + g) * DINNER + (col - DINNER)] = silu_f(acc[g]);
    }
}

// ---------------------------------------------------------------------------
// K2: conv3x3+silu -> u(fp16); xd = u@W_x; dt = softplus(...); y_init = 4*D*u.
//     y_acc SEPARATE from x_val (halo-race invariant). 4096 x 384.
// ---------------------------------------------------------------------------
__global__ void k2_conv_dt(const float* __restrict__ x_val,
                           const float* __restrict__ conv_w, const float* __restrict__ conv_b,
                           const float* __restrict__ W_x, const float* __restrict__ W_dt,
                           const float* __restrict__ b_dt, const float* __restrict__ Dp,
                           __half* __restrict__ u_out, float* __restrict__ xd_out,
                           float* __restrict__ dt32, float* __restrict__ y_acc) {
    __shared__ float us[DINNER];
    __shared__ float part[8 * 44];
    __shared__ float xdl[44];
    const int t = threadIdx.x;
    const int pos = blockIdx.x;
    const int b = pos >> 10, hw = pos & 1023, h = hw >> 5, w = hw & 31;

    float acc = conv_b[t];
#pragma unroll
    for (int i = 0; i < 3; ++i) {
        int hh = h + i - 1;
        if (hh < 0 || hh > 31) continue;
#pragma unroll
        for (int j = 0; j < 3; ++j) {
            int ww = w + j - 1;
            if (ww < 0 || ww > 31) continue;
            acc += x_val[((b * 32 + hh) * 32 + ww) * DINNER + t] * conv_w[t * 9 + i * 3 + j];
        }
    }
    float uv = silu_f(acc);
    us[t] = uv;
    u_out[pos * DINNER + t] = __float2half(uv);
    __syncthreads();

    if (t < 352) {
        int o = t % 44, p = t / 44;
        float s = 0.f;
        int j0 = p * 48;
        for (int j = j0; j < j0 + 48; ++j) s += us[j] * W_x[j * 44 + o];
        part[p * 44 + o] = s;
    }
    __syncthreads();
    if (t < 44) {
        float s = 0.f;
#pragma unroll
        for (int p = 0; p < 8; ++p) s += part[p * 44 + t];
        xd_out[pos * 48 + t] = s;
        xdl[t] = s;
    }
    __syncthreads();

    float raw = b_dt[t];
#pragma unroll
    for (int r = 0; r < DTRANK; ++r) raw += xdl[r] * W_dt[r * DINNER + t];
    dt32[pos * DINNER + t] = fmaxf(raw, 0.f) + log1pf(__expf(-fabsf(raw)));

    y_acc[pos * DINNER + t] = 4.f * Dp[t] * uv;
}

// ---------------------------------------------------------------------------
// K2cs: per-8-step chunk sums of dt in row order (o=0) and transposed (o=1).
//       Backward dirs use reversed chunk index (sums are order-independent).
//       64 blocks x 384 thr.
// ---------------------------------------------------------------------------
__global__ void k2_cs(const float* __restrict__ dt32, float* __restrict__ CS) {
    const int t = threadIdx.x;               // d
    const int bi = blockIdx.x;               // 64 = o(2) * b(4) * cg(8)
    const int cg = bi & 7, b = (bi >> 3) & 3, o = bi >> 5;
    const float* base = dt32 + b * SEQL * DINNER + t;
    for (int cc = 0; cc < 16; ++cc) {
        int c = cg * 16 + cc;
        float s = 0.f;
#pragma unroll
        for (int i = 0; i < 8; ++i) {
            int l = c * 8 + i;
            int pos = o ? swiz(l) : l;
            s += base[pos * DINNER];
        }
        CS[((size_t)((o * 4 + b) * 128 + c)) * DINNER + t] = s;
    }
}

// ---------------------------------------------------------------------------
// K3: counted-loop scan, NO convergent break. Trip count precomputed from CS
//     (conservative -120 threshold: skipped chunks are exact zeros). 2-buffer
//     manual pipeline in a single-BB counted loop. Live-region arithmetic
//     bitwise-identical to rounds 15/17. 384 blocks x 256 thr.
// ---------------------------------------------------------------------------
__device__ __forceinline__ void k3_load(const float* __restrict__ dtb,
                                        const float* __restrict__ xb,
                                        const __half* __restrict__ ub,
                                        int dir, int l0, int d, int n,
                                        float* dtv, float* Bv, float* Cv, float* uv, int* pk) {
#pragma unroll
    for (int k = 0; k < 8; ++k) {
        int pos = scan_pos(dir, l0 + k);
        pk[k]  = pos;
        dtv[k] = dtb[pos * DINNER + d];
        Bv[k]  = xb[pos * 48 + DTRANK + n];
        Cv[k]  = xb[pos * 48 + DTRANK + DSTATE + n];
        uv[k]  = __half2float(ub[pos * DINNER + d]);
    }
}

__device__ __forceinline__ void k3_compute(float A, float& cum, float& S,
                                           const float* dtv, const float* Bv,
                                           const float* Cv, const float* uv, const int* pk,
                                           float* __restrict__ yb, int d, int n) {
    float decay[8];
#pragma unroll
    for (int k = 0; k < 8; ++k) { cum += dtv[k] * A; decay[k] = __expf(cum); }
    float rc[8];
#pragma unroll
    for (int k = 0; k < 8; ++k) rc[k] = __builtin_amdgcn_rcpf(decay[k] + 1e-12f);
    float c[8];
#pragma unroll
    for (int k = 0; k < 8; ++k) {
        S += (dtv[k] * Bv[k] * uv[k]) * rc[k];
        c[k] = decay[k] * S * Cv[k];
    }
#pragma unroll
    for (int off = 1; off <= 8; off <<= 1) {
#pragma unroll
        for (int k = 0; k < 8; ++k) c[k] += __shfl_xor(c[k], off);
    }
    if (n == 0) {
#pragma unroll
        for (int k = 0; k < 8; ++k) atomicAdd(&yb[pk[k] * DINNER + d], c[k]);
    }
}

__global__ void __launch_bounds__(256, 1)
k3_scan(const __half* __restrict__ u, const float* __restrict__ xd,
        const float* __restrict__ dt32, const float* __restrict__ CS,
        const float* __restrict__ A_log, float* __restrict__ y_acc) {
    const int t = threadIdx.x;
    const int n = t & 15, dl = t >> 4;
    const int bi = blockIdx.x;
    const int chunk = bi % 24;
    const int b = (bi / 24) % 4;
    const int dir = bi / 96;
    const int d = chunk * 16 + dl;

    const float A = -__expf(A_log[d * DSTATE + n]);
    const int o = (dir >> 1) & 1;
    const int fwd = !(dir & 1);

    const __half* ub  = u    + b * SEQL * DINNER;
    const float* xb   = xd   + b * SEQL * 48;
    const float* dtb  = dt32 + b * SEQL * DINNER;
    float* yb = y_acc + b * SEQL * DINNER;

    // ---- phase 0: trip count from chunk sums (counted, branchless) ----
    const float* CSb = CS + (size_t)((o * 4 + b) * 128) * DINNER + d;
    float cumdt = 0.f;
    int last_alive = 0;
    for (int c8 = 0; c8 < 128; c8 += 8) {
        float v[8];
#pragma unroll
        for (int k = 0; k < 8; ++k) {
            int cc = c8 + k;
            int idx = fwd ? cc : 127 - cc;
            v[k] = CSb[idx * DINNER];
        }
#pragma unroll
        for (int k = 0; k < 8; ++k) {
            cumdt += v[k];
            if (A * cumdt > -120.f) last_alive = c8 + k;   // conservative vs -103.3 death
        }
    }
    float la = (float)last_alive;
#pragma unroll
    for (int off = 1; off < 64; off <<= 1) la = fmaxf(la, __shfl_xor(la, off));
    int trip = __builtin_amdgcn_readfirstlane((int)la + 1);

    // ---- main loop: counted, 2-buffer pipelined, single basic block ----
    float dtvA[8], BvA[8], CvA[8], uvA[8]; int pkA[8];
    float dtvB[8], BvB[8], CvB[8], uvB[8]; int pkB[8];

    float cum = 0.f, S = 0.f;
    const int tripPairs = (trip + 1) >> 1;
    k3_load(dtb, xb, ub, dir, 0, d, n, dtvA, BvA, CvA, uvA, pkA);
    for (int p = 0; p < tripPairs; ++p) {
        int c1 = 2 * p + 1; if (c1 > 127) c1 = 127;
        k3_load(dtb, xb, ub, dir, c1 * 8, d, n, dtvB, BvB, CvB, uvB, pkB);
        k3_compute(A, cum, S, dtvA, BvA, CvA, uvA, pkA, yb, d, n);
        int c2 = 2 * p + 2; if (c2 > 127) c2 = 127;
        k3_load(dtb, xb, ub, dir, c2 * 8, d, n, dtvA, BvA, CvA, uvA, pkA);
        k3_compute(A, cum, S, dtvB, BvB, CvB, uvB, pkB, yb, d, n);
    }
}

// ---------------------------------------------------------------------------
// K4: LayerNorm + gate + out-proj. 512 blocks x 384 thr, 8 pos/block.
// ---------------------------------------------------------------------------
__global__ void k4_out(const float* __restrict__ y_acc, const float* __restrict__ gz,
                       const float* __restrict__ gamma, const float* __restrict__ beta,
                       const float* __restrict__ W_out, float* __restrict__ out) {
    __shared__ float g_s[8 * DINNER];
    __shared__ float red[12];
    const int t = threadIdx.x;
    const int half = t / 192, tc = t % 192;
    const int lane = t & 63, wv = t >> 6;
    const int pos0 = blockIdx.x << 3;

    const float g0c = gamma[tc], g1c = gamma[tc + 192];
    const float b0c = beta[tc],  b1c = beta[tc + 192];

    for (int it = 0; it < 4; ++it) {
        int p = it * 2 + half;
        int pos = pos0 + p;
        float y0 = y_acc[pos * DINNER + tc];
        float y1 = y_acc[pos * DINNER + tc + 192];

        float s = y0 + y1;
#pragma unroll
        for (int off = 32; off > 0; off >>= 1) s += __shfl_xor(s, off);
        if (lane == 0) red[wv] = s;
        __syncthreads();
        float mu = (red[half * 3] + red[half * 3 + 1] + red[half * 3 + 2]) * (1.f / 384.f);

        float d0 = y0 - mu, d1 = y1 - mu;
        float sq = d0 * d0 + d1 * d1;
#pragma unroll
        for (int off = 32; off > 0; off >>= 1) sq += __shfl_xor(sq, off);
        if (lane == 0) red[6 + wv] = sq;
        __syncthreads();
        float var = (red[6 + half * 3] + red[6 + half * 3 + 1] + red[6 + half * 3 + 2]) * (1.f / 384.f);
        float inv = rsqrtf(var + 1e-5f);

        g_s[p * DINNER + tc]       = (d0 * inv * g0c + b0c) * gz[pos * DINNER + tc];
        g_s[p * DINNER + tc + 192] = (d1 * inv * g1c + b1c) * gz[pos * DINNER + tc + 192];
    }
    __syncthreads();

    float acc[4] = {0.f, 0.f, 0.f, 0.f};
    const int pbase = half * 4;
    for (int dd = 0; dd < DINNER; dd += 4) {
        float w0 = W_out[(dd + 0) * DMODEL + tc];
        float w1 = W_out[(dd + 1) * DMODEL + tc];
        float w2 = W_out[(dd + 2) * DMODEL + tc];
        float w3 = W_out[(dd + 3) * DMODEL + tc];
#pragma unroll
        for (int i = 0; i < 4; ++i) {
            const float4 g = *(const float4*)&g_s[(pbase + i) * DINNER + dd];
            acc[i] += g.x * w0 + g.y * w1 + g.z * w2 + g.w * w3;
        }
    }
#pragma unroll
    for (int i = 0; i < 4; ++i) out[(pos0 + pbase + i) * DMODEL + tc] = acc[i];
}

// ---------------------------------------------------------------------------
extern "C" void kernel_launch(void* const* d_in, const int* in_sizes, int n_in,
                              void* d_out, int out_size, void* d_ws, size_t ws_size,
                              hipStream_t stream) {
    (void)in_sizes; (void)n_in; (void)out_size; (void)ws_size;
    const float* x      = (const float*)d_in[0];
    const float* W_in   = (const float*)d_in[1];
    const float* conv_w = (const float*)d_in[2];
    const float* conv_b = (const float*)d_in[3];
    const float* W_x    = (const float*)d_in[4];
    const float* W_dt   = (const float*)d_in[5];
    const float* b_dt   = (const float*)d_in[6];
    const float* A_log  = (const float*)d_in[7];
    const float* Dp     = (const float*)d_in[8];
    const float* W_out  = (const float*)d_in[9];
    const float* gamma  = (const float*)d_in[10];
    const float* beta   = (const float*)d_in[11];

    // ws layout (~29.25 MB; ws ~256 MiB per fill-counter evidence):
    //  x_val fp32 : 6 MB    @ 0
    //  u     fp16 : 3 MB    @ 6291456
    //  xd    fp32 : 0.75 MB @ 9437184
    //  dt32  fp32 : 6 MB    @ 10223616
    //  gz    fp32 : 6 MB    @ 16515072
    //  y_acc fp32 : 6 MB    @ 22806528   (SEPARATE from x_val: no halo race)
    //  CS    fp32 : 1.5 MB  @ 29097984   (2 orders x 4 b x 128 chunks x 384 d)
    char* base = (char*)d_ws;
    float*  x_val = (float*)base;
    __half* u     = (__half*)(base + 6291456);
    float*  xd    = (float*)(base + 9437184);
    float*  dt32  = (float*)(base + 10223616);
    float*  gz    = (float*)(base + 16515072);
    float*  y_acc = (float*)(base + 22806528);
    float*  CS    = (float*)(base + 29097984);

    hipLaunchKernelGGL(k1_inproj, dim3(NPOS / 8 * 3), dim3(256), 0, stream, x, W_in, x_val, gz);
    hipLaunchKernelGGL(k2_conv_dt, dim3(NPOS), dim3(384), 0, stream,
                       x_val, conv_w, conv_b, W_x, W_dt, b_dt, Dp, u, xd, dt32, y_acc);
    hipLaunchKernelGGL(k2_cs, dim3(64), dim3(384), 0, stream, dt32, CS);
    hipLaunchKernelGGL(k3_scan, dim3(384), dim3(256), 0, stream,
                       u, xd, dt32, CS, A_log, y_acc);
    hipLaunchKernelGGL(k4_out, dim3(NPOS / 8), dim3(384), 0, stream,
                       y_acc, gz, gamma, beta, W_out, (float*)d_out);
}